// Round 12
// baseline (6480.540 us; speedup 1.0000x reference)
//
#include <hip/hip_runtime.h>
#include <hip/hip_fp16.h>

#define H 161
#define H2 322            // pair offset: lane L owns gate rows L and L+322
#define G4 644            // 4*H gates
#define BB 32             // batch
#define TT 1000           // time
#define M_TOT (BB*TT)     // 32000 rows
#define KXP 192           // padded K for pre GEMM (161 data + 1 bias + pad0)
#define KLP 352           // padded K for lin GEMM (322 data + pad0)
#define NWIH 1344         // padded N of wih16 (21 * 64)
#define NPAIR 84          // half2 pairs covering K padded to 168 (scan)
#define NVEC (NPAIR/4)    // 21 uint4 reads of the h vector (scan)

typedef _Float16 h2_t  __attribute__((ext_vector_type(2)));
typedef _Float16 f16x8 __attribute__((ext_vector_type(8)));
typedef float    f32x4 __attribute__((ext_vector_type(4)));

__device__ __forceinline__ h2_t bc_h2(unsigned int u) {
    return __builtin_bit_cast(h2_t, u);
}

__device__ __forceinline__ float dot2f(h2_t a, h2_t b, float c) {
#if __has_builtin(__builtin_amdgcn_fdot2)
    return __builtin_amdgcn_fdot2(a, b, c, false);
#else
    return c + (float)a[0] * (float)b[0] + (float)a[1] * (float)b[1];
#endif
}

__device__ __forceinline__ float sigm_f(float x) {
    return 1.0f / (1.0f + __expf(-x));
}
__device__ __forceinline__ float tanh_f(float x) {
    return 1.0f - 2.0f / (__expf(2.0f * x) + 1.0f);
}

// Barrier draining only LDS (lgkmcnt), not vmcnt.
__device__ __forceinline__ void bar_lds() {
    __builtin_amdgcn_sched_barrier(0);
    asm volatile("s_waitcnt lgkmcnt(0)" ::: "memory");
    __builtin_amdgcn_s_barrier();
    __builtin_amdgcn_sched_barrier(0);
}

// ---------------------------------------------------------------------------
// Convert kernels (unchanged from round 10 -- verified).
// ---------------------------------------------------------------------------
__global__ __launch_bounds__(256) void cvt_x(
    const float* __restrict__ in,    // [M][161] fp32
    __half* __restrict__ out)        // [M][192] fp16
{
    const int total = M_TOT * KXP;
    for (int idx = blockIdx.x * 256 + threadIdx.x; idx < total;
         idx += gridDim.x * 256) {
        int m = idx / KXP, k = idx - m * KXP;
        float v = (k < H) ? in[(size_t)m * H + k] : (k == H ? 1.f : 0.f);
        out[idx] = __float2half(v);
    }
}

__global__ __launch_bounds__(256) void cvt_wih(
    const float* __restrict__ wf, const float* __restrict__ wb,
    const float* __restrict__ bif, const float* __restrict__ bhf,
    const float* __restrict__ bib, const float* __restrict__ bhb,
    __half* __restrict__ out)        // [1344][192] fp16
{
    const int total = NWIH * KXP;
    for (int idx = blockIdx.x * 256 + threadIdx.x; idx < total;
         idx += gridDim.x * 256) {
        int n = idx / KXP, k = idx - n * KXP;
        float v = 0.f;
        if (n < G4) {
            v = (k < H) ? wf[(size_t)n * H + k]
                        : (k == H ? bif[n] + bhf[n] : 0.f);
        } else if (n < 2 * G4) {
            int g = n - G4;
            v = (k < H) ? wb[(size_t)g * H + k]
                        : (k == H ? bib[g] + bhb[g] : 0.f);
        }
        out[idx] = __float2half(v);
    }
}

__global__ __launch_bounds__(256) void cvt_W(
    const float* __restrict__ W,     // [161][322] fp32
    __half* __restrict__ out)        // [192][352] fp16
{
    const int total = 192 * KLP;
    for (int idx = blockIdx.x * 256 + threadIdx.x; idx < total;
         idx += gridDim.x * 256) {
        int n = idx / KLP, k = idx - n * KLP;
        float v = (n < H && k < 2 * H) ? W[(size_t)n * (2 * H) + k] : 0.f;
        out[idx] = __float2half(v);
    }
}

// ---------------------------------------------------------------------------
// pre_mfma (unchanged from round 10 -- verified).
// ---------------------------------------------------------------------------
__global__ __launch_bounds__(256) void pre_mfma(
    const __half* __restrict__ A16,    // [M][192]
    const __half* __restrict__ Wih16,  // [1344][192]
    __half* __restrict__ pre)          // [2][M_TOT][644]
{
    const int m0 = blockIdx.x * 64, n0 = blockIdx.y * 64;
    const int tid = threadIdx.x;
    const int wv = tid >> 6, l = tid & 63;
    const int wm = wv & 1, wn = wv >> 1;
    const int cl = l & 15, kg = l >> 4;

    const __half* ap = A16   + (size_t)(m0 + wm * 32 + cl) * KXP + kg * 8;
    const __half* wp = Wih16 + (size_t)(n0 + wn * 32 + cl) * KXP + kg * 8;

    f32x4 acc[2][2] = {};
    #pragma unroll
    for (int kt = 0; kt < 6; ++kt) {
        f16x8 w0 = *(const f16x8*)(wp + kt * 32);
        f16x8 w1 = *(const f16x8*)(wp + 16 * KXP + kt * 32);
        f16x8 x0 = *(const f16x8*)(ap + kt * 32);
        f16x8 x1 = *(const f16x8*)(ap + 16 * KXP + kt * 32);
        acc[0][0] = __builtin_amdgcn_mfma_f32_16x16x32_f16(w0, x0, acc[0][0], 0, 0, 0);
        acc[0][1] = __builtin_amdgcn_mfma_f32_16x16x32_f16(w0, x1, acc[0][1], 0, 0, 0);
        acc[1][0] = __builtin_amdgcn_mfma_f32_16x16x32_f16(w1, x0, acc[1][0], 0, 0, 0);
        acc[1][1] = __builtin_amdgcn_mfma_f32_16x16x32_f16(w1, x1, acc[1][1], 0, 0, 0);
    }

    #pragma unroll
    for (int sn = 0; sn < 2; ++sn)
        #pragma unroll
        for (int sm = 0; sm < 2; ++sm) {
            int n = n0 + wn * 32 + sn * 16 + kg * 4;
            int m = m0 + wm * 32 + sm * 16 + cl;
            if (n < 2 * G4) {
                int d = (n >= G4) ? 1 : 0;
                int g = n - d * G4;
                __half2 lo, hi;
                lo.x = __float2half(acc[sn][sm][0]);
                lo.y = __float2half(acc[sn][sm][1]);
                hi.x = __float2half(acc[sn][sm][2]);
                hi.y = __float2half(acc[sn][sm][3]);
                __half* dst = pre + ((size_t)d * M_TOT + m) * G4 + g;
                *(__half2*)dst = lo;
                *(__half2*)(dst + 2) = hi;
            }
        }
}

// ---------------------------------------------------------------------------
// lin_mfma (unchanged from round 10 -- verified).
// ---------------------------------------------------------------------------
__global__ __launch_bounds__(256) void lin_mfma(
    const __half* __restrict__ Hc,     // [M][352] fp16
    const __half* __restrict__ W16,    // [192][352]
    const float* __restrict__ bl,      // [161]
    const float* __restrict__ res,     // [M][161] fp32
    float* __restrict__ out,           // [M][161] fp32
    int relu)
{
    const int m0 = blockIdx.x * 64, n0 = blockIdx.y * 64;
    const int tid = threadIdx.x;
    const int wv = tid >> 6, l = tid & 63;
    const int wm = wv & 1, wn = wv >> 1;
    const int cl = l & 15, kg = l >> 4;

    const __half* ap = Hc  + (size_t)(m0 + wm * 32 + cl) * KLP + kg * 8;
    const __half* wp = W16 + (size_t)(n0 + wn * 32 + cl) * KLP + kg * 8;

    f32x4 acc[2][2] = {};
    #pragma unroll
    for (int kt = 0; kt < 11; ++kt) {
        f16x8 w0 = *(const f16x8*)(wp + kt * 32);
        f16x8 w1 = *(const f16x8*)(wp + 16 * KLP + kt * 32);
        f16x8 x0 = *(const f16x8*)(ap + kt * 32);
        f16x8 x1 = *(const f16x8*)(ap + 16 * KLP + kt * 32);
        acc[0][0] = __builtin_amdgcn_mfma_f32_16x16x32_f16(w0, x0, acc[0][0], 0, 0, 0);
        acc[0][1] = __builtin_amdgcn_mfma_f32_16x16x32_f16(w0, x1, acc[0][1], 0, 0, 0);
        acc[1][0] = __builtin_amdgcn_mfma_f32_16x16x32_f16(w1, x0, acc[1][0], 0, 0, 0);
        acc[1][1] = __builtin_amdgcn_mfma_f32_16x16x32_f16(w1, x1, acc[1][1], 0, 0, 0);
    }

    #pragma unroll
    for (int sn = 0; sn < 2; ++sn)
        #pragma unroll
        for (int sm = 0; sm < 2; ++sm) {
            int nb = n0 + wn * 32 + sn * 16 + kg * 4;
            int m  = m0 + wm * 32 + sm * 16 + cl;
            #pragma unroll
            for (int r = 0; r < 4; ++r) {
                int n = nb + r;
                if (n < H) {
                    float v = acc[sn][sm][r] + bl[n];
                    if (relu) v = fmaxf(v, 0.f);
                    v += res[(size_t)m * H + n];
                    out[(size_t)m * H + n] = v;
                }
            }
        }
}

// ---------------------------------------------------------------------------
// lstm_scan v11: 384 threads = 6 waves, 2 gate rows per lane (L, L+322) --
// R9's verified pair structure -- with the 168 packed-half2 weights held in
// AGPRs via explicit v_accvgpr_write/read inline asm. This resolves the
// 9-round pincer: 11-wave layouts are LDS-broadcast-bound (1850 cyc/step);
// 6-wave layouts need 168 regs/lane which the allocator scratch-spills
// (R9: VGPR=128 + reload tax). Explicit AGPR placement costs a deterministic
// accvgpr_read (1 VALU op) per weight per step and halves the broadcast:
//   issue ~= 2 waves x ~390 inst x 2 cyc = 1560 cyc  (busiest SIMD)
//   LDS   ~= 126 x ds_read_b128 ~= 1000 cyc/CU       (was 1850)
// launch_bounds(384,2): 2 waves/SIMD -> 256-reg unified budget = 168 AGPR
// + ~80 arch. h broadcast = R1's verified 21x uint4 loop; gsh exchange,
// clamps, 2-step prefetch, lgkm-only barriers identical to R9.
// ---------------------------------------------------------------------------
__global__ __launch_bounds__(384, 2) void lstm_scan(
    const __half* __restrict__ pre,      // [2][M_TOT][G4] gate-major
    const float* __restrict__ whh_f,
    const float* __restrict__ whh_b,
    __half* __restrict__ hcat)           // [M_TOT][KLP] fp16
{
    const int b = blockIdx.x;            // 0..31
    const int d = blockIdx.y;            // 0,1
    const int tid = threadIdx.x;
    const float* whh = d ? whh_b : whh_f;

    __shared__ __align__(16) unsigned int h_sh[NPAIR];  // 168 halves
    __shared__ float2 gsh[H];                           // (fg, og) per hid

    const bool active = tid < H2;
    const int L = active ? tid : (H2 - 1);   // clamp lanes 322..383
    const bool low = (L < H);                // i/g lane (owns hid L)

    // Two weight rows packed half2, K padded to 168, written to AGPRs.
    // Rows: L in [0,322) = i|f block; L+322 = g|o block (R9-verified map).
    unsigned int wa0[NPAIR], wa1[NPAIR];
    {
        const float* r0 = whh + (size_t)L * H;
        const float* r1 = whh + (size_t)(L + H2) * H;
        #pragma unroll
        for (int i = 0; i < NPAIR; ++i) {
            int k = 2 * i;
            float a0 = (k < H) ? r0[k] : 0.f;
            float a1 = (k + 1 < H) ? r0[k + 1] : 0.f;
            float b0 = (k < H) ? r1[k] : 0.f;
            float b1 = (k + 1 < H) ? r1[k + 1] : 0.f;
            h2_t v0; v0[0] = (_Float16)a0; v0[1] = (_Float16)a1;
            h2_t v1; v1[0] = (_Float16)b0; v1[1] = (_Float16)b1;
            unsigned int u0 = __builtin_bit_cast(unsigned int, v0);
            unsigned int u1 = __builtin_bit_cast(unsigned int, v1);
            asm volatile("v_accvgpr_write_b32 %0, %1" : "=a"(wa0[i]) : "v"(u0));
            asm volatile("v_accvgpr_write_b32 %0, %1" : "=a"(wa1[i]) : "v"(u1));
        }
    }
    if (tid < NPAIR) h_sh[tid] = 0u;

    float c = 0.f;
    const __half* pb = pre + ((size_t)d * M_TOT + (size_t)b * TT) * G4;

    // Load the lane's two pre values (gates L and L+322) for logical step
    // tt_, clamped; stale epilogue prefetches are never consumed.
    #define LDP2(tt_, OL, OH) {                                             \
        int tc_ = ((tt_) < TT) ? (tt_) : (TT - 1);                          \
        int t_  = d ? (TT - 1 - tc_) : tc_;                                 \
        size_t o_ = (size_t)t_ * G4;                                        \
        OL = pb[o_ + L];                                                    \
        OH = pb[o_ + L + H2];                                               \
    }

    __half p0l, p0h, p1l, p1h;
    LDP2(0, p0l, p0h)
    LDP2(1, p1l, p1h)
    __syncthreads();

    #define STEP(TTT, PL, PH) {                                             \
        int t = d ? (TT - 1 - (TTT)) : (TTT);                               \
        float a0 = __half2float(PL), a0b = 0.f;                             \
        float a1 = __half2float(PH), a1b = 0.f;                             \
        LDP2((TTT) + 2, PL, PH)          /* 2-steps-ahead prefetch */       \
        const uint4* h4 = (const uint4*)h_sh;                               \
        _Pragma("unroll")                                                   \
        for (int i = 0; i < NVEC; ++i) {                                    \
            uint4 hh = h4[i];                                               \
            unsigned int u0, u1;                                            \
            asm volatile("v_accvgpr_read_b32 %0, %1" : "=v"(u0) : "a"(wa0[4*i+0])); \
            asm volatile("v_accvgpr_read_b32 %0, %1" : "=v"(u1) : "a"(wa1[4*i+0])); \
            a0  = dot2f(bc_h2(u0), bc_h2(hh.x), a0);                        \
            a1  = dot2f(bc_h2(u1), bc_h2(hh.x), a1);                        \
            asm volatile("v_accvgpr_read_b32 %0, %1" : "=v"(u0) : "a"(wa0[4*i+1])); \
            asm volatile("v_accvgpr_read_b32 %0, %1" : "=v"(u1) : "a"(wa1[4*i+1])); \
            a0b = dot2f(bc_h2(u0), bc_h2(hh.y), a0b);                       \
            a1b = dot2f(bc_h2(u1), bc_h2(hh.y), a1b);                       \
            asm volatile("v_accvgpr_read_b32 %0, %1" : "=v"(u0) : "a"(wa0[4*i+2])); \
            asm volatile("v_accvgpr_read_b32 %0, %1" : "=v"(u1) : "a"(wa1[4*i+2])); \
            a0  = dot2f(bc_h2(u0), bc_h2(hh.z), a0);                        \
            a1  = dot2f(bc_h2(u1), bc_h2(hh.z), a1);                        \
            asm volatile("v_accvgpr_read_b32 %0, %1" : "=v"(u0) : "a"(wa0[4*i+3])); \
            asm volatile("v_accvgpr_read_b32 %0, %1" : "=v"(u1) : "a"(wa1[4*i+3])); \
            a0b = dot2f(bc_h2(u0), bc_h2(hh.w), a0b);                       \
            a1b = dot2f(bc_h2(u1), bc_h2(hh.w), a1b);                       \
        }                                                                   \
        a0 += a0b; a1 += a1b;                                               \
        float act0 = sigm_f(a0);                 /* i (low) or f (high) */  \
        float xs = low ? (a1 + a1) : a1;                                    \
        float ss = sigm_f(xs);                                              \
        float act1 = low ? (ss + ss - 1.0f) : ss; /* g=tanh or o=sigm */    \
        if (active && !low) gsh[L - H] = make_float2(act0, act1);           \
        bar_lds();                                                          \
        if (tid < H) {                                                      \
            float2 fo = gsh[tid];                 /* (fg, og) */            \
            c = fo.x * c + act0 * act1;           /* own ig, gg */          \
            float hval = fo.y * tanh_f(c);                                  \
            __half h16 = __float2half(hval);                                \
            hcat[((size_t)b * TT + t) * KLP + (size_t)d * H + tid] = h16;   \
            ((__half*)h_sh)[tid] = h16;                                     \
        }                                                                   \
        bar_lds();                                                          \
    }

    for (int base = 0; base < TT; base += 2) {
        STEP(base,     p0l, p0h)
        STEP(base + 1, p1l, p1h)
    }
    #undef STEP
    #undef LDP2
}

extern "C" void kernel_launch(void* const* d_in, const int* in_sizes, int n_in,
                              void* d_out, int out_size, void* d_ws, size_t ws_size,
                              hipStream_t stream) {
    const float* x = (const float*)d_in[0];

    char* ws = (char*)d_ws;
    __half* pre    = (__half*)ws;                                   // 82.4 MB
    __half* hcat16 = (__half*)(ws + (size_t)2 * M_TOT * G4 * 2);    // 22.5 MB
    __half* A16    = (__half*)((char*)hcat16 + (size_t)M_TOT * KLP * 2); // 12.3 MB
    __half* wih16  = (__half*)((char*)A16 + (size_t)M_TOT * KXP * 2);    // 0.5 MB
    __half* W16    = (__half*)((char*)wih16 + (size_t)NWIH * KXP * 2);   // 0.14 MB
    float*  bufA   = (float*)((char*)W16 + (size_t)192 * KLP * 2);       // 20.6 MB
    float*  bufB   = bufA + (size_t)M_TOT * H;                           // 20.6 MB

    // Zero hcat16 once: covers the k-pad (322..351) the scan never writes.
    hipMemsetAsync(hcat16, 0, (size_t)M_TOT * KLP * sizeof(__half), stream);

    const float* cur = x;
    float* outs[3] = {bufA, bufB, (float*)d_out};

    for (int l = 0; l < 3; ++l) {
        const float* const* p = (const float* const*)(d_in + 1 + 10 * l);
        // p: wih_f whh_f bih_f bhh_f wih_b whh_b bih_b bhh_b W bl
        cvt_x  <<<2048, 256, 0, stream>>>(cur, A16);
        cvt_wih<<<256, 256, 0, stream>>>(p[0], p[4], p[2], p[3], p[6], p[7], wih16);
        cvt_W  <<<64, 256, 0, stream>>>(p[8], W16);

        pre_mfma<<<dim3(M_TOT / 64, 21), 256, 0, stream>>>(A16, wih16, pre);
        lstm_scan<<<dim3(32, 2), 384, 0, stream>>>(pre, p[1], p[5], hcat16);
        lin_mfma<<<dim3(M_TOT / 64, 3), 256, 0, stream>>>(
            hcat16, W16, p[9], cur, outs[l], (l < 2) ? 1 : 0);
        cur = outs[l];
    }
}

// Round 13
// 3477.885 us; speedup vs baseline: 1.8634x; 1.8634x over previous
//
#include <hip/hip_runtime.h>
#include <hip/hip_fp16.h>

#define H 161
#define G4 644            // 4*H gates
#define BB 32             // batch
#define TT 1000           // time
#define M_TOT (BB*TT)     // 32000 rows
#define KXP 192           // padded K for pre GEMM (161 data + 1 bias + pad0)
#define KLP 352           // padded K for lin GEMM (322 data + pad0)
#define NWIH 1344         // padded N of wih16 (21 * 64)
#define NPAIR 84          // half2 pairs covering K padded to 168 (scan)
#define NVEC (NPAIR/4)    // 21 uint4 reads of the h vector (scan)

typedef _Float16 h2_t  __attribute__((ext_vector_type(2)));
typedef _Float16 f16x8 __attribute__((ext_vector_type(8)));
typedef float    f32x4 __attribute__((ext_vector_type(4)));

__device__ __forceinline__ h2_t bc_h2(unsigned int u) {
    return __builtin_bit_cast(h2_t, u);
}

__device__ __forceinline__ float dot2f(h2_t a, h2_t b, float c) {
#if __has_builtin(__builtin_amdgcn_fdot2)
    return __builtin_amdgcn_fdot2(a, b, c, false);
#else
    return c + (float)a[0] * (float)b[0] + (float)a[1] * (float)b[1];
#endif
}

__device__ __forceinline__ float tanh_f(float x) {
    return 1.0f - 2.0f / (__expf(2.0f * x) + 1.0f);
}

// Barrier draining only LDS (lgkmcnt), not vmcnt.
__device__ __forceinline__ void bar_lds() {
    __builtin_amdgcn_sched_barrier(0);
    asm volatile("s_waitcnt lgkmcnt(0)" ::: "memory");
    __builtin_amdgcn_s_barrier();
    __builtin_amdgcn_sched_barrier(0);
}

// ---------------------------------------------------------------------------
// cvt_x: layer-0 input only. Sets bias column (k=161 -> 1.0) and zero pad;
// lin_mfma's fused A16 write (layers 1,2) only touches k<161, so the bias
// column and pad persist across layers.
// ---------------------------------------------------------------------------
__global__ __launch_bounds__(256) void cvt_x(
    const float* __restrict__ in,    // [M][161] fp32
    __half* __restrict__ out)        // [M][192] fp16
{
    const int total = M_TOT * KXP;
    for (int idx = blockIdx.x * 256 + threadIdx.x; idx < total;
         idx += gridDim.x * 256) {
        int m = idx / KXP, k = idx - m * KXP;
        float v = (k < H) ? in[(size_t)m * H + k] : (k == H ? 1.f : 0.f);
        out[idx] = __float2half(v);
    }
}

// ---------------------------------------------------------------------------
// cvt_wih3 / cvt_W3: all three layers' weight conversions in one launch
// each (blockIdx.y = layer). Weights are activation-independent, so these
// run once, before the layer loop.
// ---------------------------------------------------------------------------
__global__ __launch_bounds__(256) void cvt_wih3(
    const float* __restrict__ wf0, const float* __restrict__ wb0,
    const float* __restrict__ bif0, const float* __restrict__ bhf0,
    const float* __restrict__ bib0, const float* __restrict__ bhb0,
    const float* __restrict__ wf1, const float* __restrict__ wb1,
    const float* __restrict__ bif1, const float* __restrict__ bhf1,
    const float* __restrict__ bib1, const float* __restrict__ bhb1,
    const float* __restrict__ wf2, const float* __restrict__ wb2,
    const float* __restrict__ bif2, const float* __restrict__ bhf2,
    const float* __restrict__ bib2, const float* __restrict__ bhb2,
    __half* __restrict__ out)        // [3][1344][192] fp16
{
    const int l = blockIdx.y;
    const float* wf  = (l == 0) ? wf0  : (l == 1) ? wf1  : wf2;
    const float* wb  = (l == 0) ? wb0  : (l == 1) ? wb1  : wb2;
    const float* bif = (l == 0) ? bif0 : (l == 1) ? bif1 : bif2;
    const float* bhf = (l == 0) ? bhf0 : (l == 1) ? bhf1 : bhf2;
    const float* bib = (l == 0) ? bib0 : (l == 1) ? bib1 : bib2;
    const float* bhb = (l == 0) ? bhb0 : (l == 1) ? bhb1 : bhb2;
    __half* o = out + (size_t)l * NWIH * KXP;

    const int total = NWIH * KXP;
    for (int idx = blockIdx.x * 256 + threadIdx.x; idx < total;
         idx += gridDim.x * 256) {
        int n = idx / KXP, k = idx - n * KXP;
        float v = 0.f;
        if (n < G4) {
            v = (k < H) ? wf[(size_t)n * H + k]
                        : (k == H ? bif[n] + bhf[n] : 0.f);
        } else if (n < 2 * G4) {
            int g = n - G4;
            v = (k < H) ? wb[(size_t)g * H + k]
                        : (k == H ? bib[g] + bhb[g] : 0.f);
        }
        o[idx] = __float2half(v);
    }
}

__global__ __launch_bounds__(256) void cvt_W3(
    const float* __restrict__ W0, const float* __restrict__ W1,
    const float* __restrict__ W2,
    __half* __restrict__ out)        // [3][192][352] fp16
{
    const int l = blockIdx.y;
    const float* W = (l == 0) ? W0 : (l == 1) ? W1 : W2;
    __half* o = out + (size_t)l * 192 * KLP;

    const int total = 192 * KLP;
    for (int idx = blockIdx.x * 256 + threadIdx.x; idx < total;
         idx += gridDim.x * 256) {
        int n = idx / KLP, k = idx - n * KLP;
        float v = (n < H && k < 2 * H) ? W[(size_t)n * (2 * H) + k] : 0.f;
        o[idx] = __float2half(v);
    }
}

// ---------------------------------------------------------------------------
// pre_mfma: R10's verified kernel with A-fragment reuse: each block holds
// its A-frags in registers (48 VGPRs) and loops 3 n-tiles (grid.y 21 -> 7),
// cutting A16 L3 re-reads 21x -> 7x. Per-tile fragment/epilogue code is
// identical to the verified R10 version.
// ---------------------------------------------------------------------------
__global__ __launch_bounds__(256) void pre_mfma(
    const __half* __restrict__ A16,    // [M][192]
    const __half* __restrict__ Wih16,  // [1344][192] (one layer)
    __half* __restrict__ pre)          // [2][M_TOT][644]
{
    const int m0 = blockIdx.x * 64;
    const int n0b = blockIdx.y * 192;
    const int tid = threadIdx.x;
    const int wv = tid >> 6, l = tid & 63;
    const int wm = wv & 1, wn = wv >> 1;
    const int cl = l & 15, kg = l >> 4;

    const __half* ap = A16 + (size_t)(m0 + wm * 32 + cl) * KXP + kg * 8;
    f16x8 xa0[6], xa1[6];
    #pragma unroll
    for (int kt = 0; kt < 6; ++kt) {
        xa0[kt] = *(const f16x8*)(ap + kt * 32);
        xa1[kt] = *(const f16x8*)(ap + 16 * KXP + kt * 32);
    }

    for (int nb = 0; nb < 3; ++nb) {
        const int n0 = n0b + nb * 64;
        const __half* wp = Wih16 + (size_t)(n0 + wn * 32 + cl) * KXP + kg * 8;

        f32x4 acc[2][2] = {};
        #pragma unroll
        for (int kt = 0; kt < 6; ++kt) {
            f16x8 w0 = *(const f16x8*)(wp + kt * 32);
            f16x8 w1 = *(const f16x8*)(wp + 16 * KXP + kt * 32);
            acc[0][0] = __builtin_amdgcn_mfma_f32_16x16x32_f16(w0, xa0[kt], acc[0][0], 0, 0, 0);
            acc[0][1] = __builtin_amdgcn_mfma_f32_16x16x32_f16(w0, xa1[kt], acc[0][1], 0, 0, 0);
            acc[1][0] = __builtin_amdgcn_mfma_f32_16x16x32_f16(w1, xa0[kt], acc[1][0], 0, 0, 0);
            acc[1][1] = __builtin_amdgcn_mfma_f32_16x16x32_f16(w1, xa1[kt], acc[1][1], 0, 0, 0);
        }

        #pragma unroll
        for (int sn = 0; sn < 2; ++sn)
            #pragma unroll
            for (int sm = 0; sm < 2; ++sm) {
                int n = n0 + wn * 32 + sn * 16 + kg * 4;
                int m = m0 + wm * 32 + sm * 16 + cl;
                if (n < 2 * G4) {
                    int d = (n >= G4) ? 1 : 0;
                    int g = n - d * G4;
                    __half2 lo, hi;
                    lo.x = __float2half(acc[sn][sm][0]);
                    lo.y = __float2half(acc[sn][sm][1]);
                    hi.x = __float2half(acc[sn][sm][2]);
                    hi.y = __float2half(acc[sn][sm][3]);
                    __half* dst = pre + ((size_t)d * M_TOT + m) * G4 + g;
                    *(__half2*)dst = lo;
                    *(__half2*)(dst + 2) = hi;
                }
            }
    }
}

// ---------------------------------------------------------------------------
// lin_mfma: R10's verified kernel + fused fp16 A16 write (replaces cvt_x
// for the next layer). A16 write only touches k<161; bias column and pad
// were set once by cvt_x at layer 0.
// ---------------------------------------------------------------------------
__global__ __launch_bounds__(256) void lin_mfma(
    const __half* __restrict__ Hc,     // [M][352] fp16
    const __half* __restrict__ W16,    // [192][352] (one layer)
    const float* __restrict__ bl,      // [161]
    const float* __restrict__ res,     // [M][161] fp32
    float* __restrict__ out,           // [M][161] fp32
    __half* __restrict__ A16out,       // [M][192] fp16 (next layer's A)
    int relu, int wr_a16)
{
    const int m0 = blockIdx.x * 64, n0 = blockIdx.y * 64;
    const int tid = threadIdx.x;
    const int wv = tid >> 6, l = tid & 63;
    const int wm = wv & 1, wn = wv >> 1;
    const int cl = l & 15, kg = l >> 4;

    const __half* ap = Hc  + (size_t)(m0 + wm * 32 + cl) * KLP + kg * 8;
    const __half* wp = W16 + (size_t)(n0 + wn * 32 + cl) * KLP + kg * 8;

    f32x4 acc[2][2] = {};
    #pragma unroll
    for (int kt = 0; kt < 11; ++kt) {
        f16x8 w0 = *(const f16x8*)(wp + kt * 32);
        f16x8 w1 = *(const f16x8*)(wp + 16 * KLP + kt * 32);
        f16x8 x0 = *(const f16x8*)(ap + kt * 32);
        f16x8 x1 = *(const f16x8*)(ap + 16 * KLP + kt * 32);
        acc[0][0] = __builtin_amdgcn_mfma_f32_16x16x32_f16(w0, x0, acc[0][0], 0, 0, 0);
        acc[0][1] = __builtin_amdgcn_mfma_f32_16x16x32_f16(w0, x1, acc[0][1], 0, 0, 0);
        acc[1][0] = __builtin_amdgcn_mfma_f32_16x16x32_f16(w1, x0, acc[1][0], 0, 0, 0);
        acc[1][1] = __builtin_amdgcn_mfma_f32_16x16x32_f16(w1, x1, acc[1][1], 0, 0, 0);
    }

    #pragma unroll
    for (int sn = 0; sn < 2; ++sn)
        #pragma unroll
        for (int sm = 0; sm < 2; ++sm) {
            int nb = n0 + wn * 32 + sn * 16 + kg * 4;
            int m  = m0 + wm * 32 + sm * 16 + cl;
            #pragma unroll
            for (int r = 0; r < 4; ++r) {
                int n = nb + r;
                if (n < H) {
                    float v = acc[sn][sm][r] + bl[n];
                    if (relu) v = fmaxf(v, 0.f);
                    v += res[(size_t)m * H + n];
                    out[(size_t)m * H + n] = v;
                    if (wr_a16)
                        A16out[(size_t)m * KXP + n] = __float2half(v);
                }
            }
        }
}

// ---------------------------------------------------------------------------
// lstm_scan: round 10's verified 995 us kernel, byte-identical.
// (Best of 12 rounds; all register-blocked/readlane/MFMA/explicit-AGPR
// variants measured slower -- see session ledger.)
// ---------------------------------------------------------------------------
__global__ __launch_bounds__(704, 3) void lstm_scan(
    const __half* __restrict__ pre,      // [2][M_TOT][G4]
    const float* __restrict__ whh_f,
    const float* __restrict__ whh_b,
    __half* __restrict__ hcat)           // [M_TOT][KLP] fp16
{
    const int b = blockIdx.x;            // 0..31
    const int d = blockIdx.y;            // 0,1
    const int tid = threadIdx.x;
    const float* whh = d ? whh_b : whh_f;

    __shared__ __align__(16) unsigned int h_sh[NPAIR];  // 168 halves
    __shared__ float gate_sh[G4];

    const bool active = tid < G4;
    h2_t w[NPAIR];
    if (active) {
        const float* row = whh + (size_t)tid * H;
        #pragma unroll
        for (int i = 0; i < NPAIR; ++i) {
            float w0 = (2 * i < H) ? row[2 * i] : 0.f;
            float w1 = (2 * i + 1 < H) ? row[2 * i + 1] : 0.f;
            h2_t v; v[0] = (_Float16)w0; v[1] = (_Float16)w1;
            w[i] = v;
        }
    }
    if (tid < NPAIR) h_sh[tid] = 0u;
    float c = 0.f;
    const __half* pb = pre + ((size_t)d * M_TOT + (size_t)b * TT) * G4;
    const bool is_g_gate = (tid >= 2 * H) && (tid < 3 * H);

    int t0 = d ? (TT - 1) : 0;
    __half pc = __half(0.0f);
    if (active) pc = pb[(long long)t0 * G4 + tid];
    __syncthreads();

    for (int ttt = 0; ttt < TT; ++ttt) {
        int t = d ? (TT - 1 - ttt) : ttt;
        // Prefetch next step's pre. Unclamped t+-1 stays inside the
        // [2][M_TOT][G4] buffer for every (b,d); final stale prefetch
        // is never consumed.
        int tn = d ? (t - 1) : (t + 1);
        __half pn = __half(0.0f);
        if (active) pn = pb[(long long)tn * G4 + tid];

        if (active) {
            float a0 = 0.f, a1 = 0.f, a2 = 0.f, a3 = 0.f;
            const uint4* hv = (const uint4*)h_sh;
            #pragma unroll
            for (int i = 0; i < NVEC; ++i) {
                uint4 hh = hv[i];
                a0 = dot2f(w[4 * i + 0], bc_h2(hh.x), a0);
                a1 = dot2f(w[4 * i + 1], bc_h2(hh.y), a1);
                a2 = dot2f(w[4 * i + 2], bc_h2(hh.z), a2);
                a3 = dot2f(w[4 * i + 3], bc_h2(hh.w), a3);
            }
            float acc = __half2float(pc) + (a0 + a1) + (a2 + a3);
            // Single-exp activation: tanh(x) = 2*sigmoid(2x) - 1.
            float xs = is_g_gate ? (acc + acc) : acc;
            float s = 1.0f / (1.0f + __expf(-xs));
            gate_sh[tid] = is_g_gate ? (s + s - 1.0f) : s;
        }
        bar_lds();
        if (tid < H) {
            float ig = gate_sh[tid];
            float fg = gate_sh[tid + H];
            float gg = gate_sh[tid + 2 * H];
            float og = gate_sh[tid + 3 * H];
            c = fg * c + ig * gg;
            float h = og * tanh_f(c);
            __half h16 = __float2half(h);
            hcat[((size_t)b * TT + t) * KLP + (size_t)d * H + tid] = h16;
            ((__half*)h_sh)[tid] = h16;
        }
        bar_lds();
        pc = pn;
    }
}

extern "C" void kernel_launch(void* const* d_in, const int* in_sizes, int n_in,
                              void* d_out, int out_size, void* d_ws, size_t ws_size,
                              hipStream_t stream) {
    const float* x = (const float*)d_in[0];

    char* ws = (char*)d_ws;
    __half* pre    = (__half*)ws;                                     // 82.4 MB
    __half* hcat16 = (__half*)(ws + (size_t)2 * M_TOT * G4 * 2);      // 22.5 MB
    __half* A16    = (__half*)((char*)hcat16 + (size_t)M_TOT * KLP * 2); // 12.3 MB
    __half* wih3   = (__half*)((char*)A16 + (size_t)M_TOT * KXP * 2);    // 1.55 MB
    __half* W3     = (__half*)((char*)wih3 + (size_t)3 * NWIH * KXP * 2);// 0.41 MB
    float*  bufA   = (float*)((char*)W3 + (size_t)3 * 192 * KLP * 2);    // 20.6 MB
    float*  bufB   = bufA + (size_t)M_TOT * H;                           // 20.6 MB

    const float* const* p0 = (const float* const*)(d_in + 1);
    const float* const* p1 = (const float* const*)(d_in + 11);
    const float* const* p2 = (const float* const*)(d_in + 21);
    // each p: wih_f whh_f bih_f bhh_f wih_b whh_b bih_b bhh_b W bl

    // One-time setup: zero hcat16 pad, convert layer-0 input, convert all
    // weights for all three layers.
    hipMemsetAsync(hcat16, 0, (size_t)M_TOT * KLP * sizeof(__half), stream);
    cvt_x<<<2048, 256, 0, stream>>>(x, A16);
    cvt_wih3<<<dim3(256, 3), 256, 0, stream>>>(
        p0[0], p0[4], p0[2], p0[3], p0[6], p0[7],
        p1[0], p1[4], p1[2], p1[3], p1[6], p1[7],
        p2[0], p2[4], p2[2], p2[3], p2[6], p2[7], wih3);
    cvt_W3<<<dim3(64, 3), 256, 0, stream>>>(p0[8], p1[8], p2[8], W3);

    const float* const* ps[3] = {p0, p1, p2};
    const float* cur = x;
    float* outs[3] = {bufA, bufB, (float*)d_out};

    for (int l = 0; l < 3; ++l) {
        const float* const* p = ps[l];
        pre_mfma<<<dim3(M_TOT / 64, 7), 256, 0, stream>>>(
            A16, wih3 + (size_t)l * NWIH * KXP, pre);
        lstm_scan<<<dim3(32, 2), 704, 0, stream>>>(pre, p[1], p[5], hcat16);
        lin_mfma<<<dim3(M_TOT / 64, 3), 256, 0, stream>>>(
            hcat16, W3 + (size_t)l * 192 * KLP, p[9], cur, outs[l], A16,
            (l < 2) ? 1 : 0, (l < 2) ? 1 : 0);
        cur = outs[l];
    }
}